// Round 3
// baseline (4708.046 us; speedup 1.0000x reference)
//
#include <hip/hip_runtime.h>
#include <hip/hip_bf16.h>
#include <hip/hip_fp16.h>

#define NN 4096
#define NGROW 8
#define NPOL 2
#define NITER (NGROW + NPOL)
#define NPOW 12
#define NKT (NN / 64)     // 64 K-tiles of BK=64
#define NTRI 136          // 16*17/2 lower-triangle 256-tiles
#define PRESCALE 32.0f    // keeps pre-rescale A entries in f16 normal range

using f16 = _Float16;
typedef __attribute__((ext_vector_type(4))) float f32x4;
typedef __attribute__((ext_vector_type(8))) f16 h16x8;

// ---------------------------------------------------------------------------
// async global->LDS, 16B per lane. LDS side MUST be wave-uniform base + lane*16.
// ---------------------------------------------------------------------------
__device__ inline void gl_lds16(const void* g, void* l) {
  __builtin_amdgcn_global_load_lds(
      (const __attribute__((address_space(1))) unsigned int*)(unsigned long long)(uintptr_t)g,
      (__attribute__((address_space(3))) unsigned int*)(uintptr_t)l,
      16, 0, 0);
}

// ---------------------------------------------------------------------------
// NT GEMM, 256x256 tile, BK=64, 8-phase schedule with SINGLE barrier per
// phase (the R2 post-mortem: paired barriers force strict LDS/MFMA
// alternation -> measured MfmaUtil 42.3% == the zero-overlap bound 42.4%.
// One barrier per phase lets reads(p+1) issue right after MFMA(p), so the
// LDS stream of the next phase hides under the matrix pipe via wave skew).
//
//   C[i,j] = sum_k P[i,k]*Q[j,k]; epilogue out = alpha*aux + beta*acc.
//   EPI==0 -> f16 out, EPI==1 -> f32 out. TRI==1: 136 lower-triangle blocks,
//   fused mirror write (products are symmetric).
//
// Per K-tile t (buf=t&1), phase q computes C-quadrant q (16 MFMA):
//   p0: ds B(t)[8]+A-q0[4]; stage A1,A3(t+1)->nbuf; lgkm(8); BAR; lgkm(0); MFMA
//   p1: ds A-q1[4];         stage B0,B1(t+2)->buf;           BAR; lgkm(0); MFMA
//   p2: ds A-q2[4];         stage B2,B3(t+2)->buf;           BAR; lgkm(0); MFMA
//   p3: ds A-q3[4];         stage A0,A2(t+2)->buf;           BAR; lgkm(0); MFMA;
//       VMCNT(6); BAR   <- tile boundary: vmcnt is per-wave, so the barrier
//                          AFTER it is what makes t+1's staged data visible
//                          cross-wave before anyone reads it.
// Write-hazards (single-barrier proof): stage(p) is issued after bar(p-1);
// each overwritten region's last ds_read was issued before bar(q), q<=p-1:
//   B(t) read p0, staged p1; A-even(t) read <=p1, staged p3; A-odd(t-1)
//   read t-1 p3, staged t p0. The in-flight-read vs returning-write margin
//   is >= 1 barrier + a full memory round trip.
// vmcnt ledger (2 loads/thread/phase): carry-in 6 = {B01,B23,A02}(t+1);
// issue 8 during t; VMCNT(6) drains 8 oldest = all of t+1's data.
// Peel: NKT-2 ends VMCNT(0); NKT-1 stages/waits nothing.
// ---------------------------------------------------------------------------
template <int EPI, int TRI>
__global__ __launch_bounds__(512, 2) void gemm_nt(
    const f16* __restrict__ P, const f16* __restrict__ Q,
    void* __restrict__ Out, const f16* __restrict__ aux,
    float alpha, float beta) {
  int bi, bj;
  if (TRI) {
    const int t = blockIdx.x;
    int r = (int)((sqrtf(8.0f * (float)t + 1.0f) - 1.0f) * 0.5f);
    while ((r + 1) * (r + 2) / 2 <= t) ++r;
    while (r * (r + 1) / 2 > t) --r;
    bi = r;
    bj = t - r * (r + 1) / 2;
  } else {
    bi = blockIdx.x;
    bj = blockIdx.y;
  }

  __shared__ f16 lA[2][256 * 64];   // 32 KB x2
  __shared__ f16 lB[2][256 * 64];   // 32 KB x2  (total 128 KiB)

  const int tid = threadIdx.x;
  const int lane = tid & 63;
  const int wv = tid >> 6;      // 0..7
  const int wr = wv >> 2;       // 0..1  (M)
  const int wc = wv & 3;        // 0..3  (N)
  const int m = lane & 15;
  const int qd = lane >> 4;     // 0..3
  const int srow = tid >> 3;    // 0..63 row within a 64-row stage unit
  const int schk = tid & 7;     // 8-f16 chunk within row

  f32x4 acc[8][4] = {};

// stage unit u (64 rows) of A/B for K-offset kk into buffer b_.
// global source pre-swizzled (chunk ^ row&7), LDS dest linear (G21).
#define STAGE_A(u_, kk_, b_)                                                  \
  do {                                                                        \
    const int rr_ = (u_)*64 + srow;                                           \
    gl_lds16(P + (size_t)(bi * 256 + rr_) * NN + (kk_) + ((schk ^ (srow & 7)) * 8), \
             &lA[b_][(u_)*4096 + tid * 8]);                                   \
  } while (0)
#define STAGE_B(u_, kk_, b_)                                                  \
  do {                                                                        \
    const int rr_ = (u_)*64 + srow;                                           \
    gl_lds16(Q + (size_t)(bj * 256 + rr_) * NN + (kk_) + ((schk ^ (srow & 7)) * 8), \
             &lB[b_][(u_)*4096 + tid * 8]);                                   \
  } while (0)

#define READ_B_FR(b_)                                                         \
  do {                                                                        \
    _Pragma("unroll") for (int cf = 0; cf < 4; ++cf)                          \
    _Pragma("unroll") for (int ks = 0; ks < 2; ++ks) {                        \
      const int rb = wc * 64 + cf * 16 + m;                                   \
      const int cb = (ks * 4 + qd) ^ (rb & 7);                                \
      bv[cf][ks] = *(const h16x8*)&lB[b_][rb * 64 + cb * 8];                  \
    }                                                                         \
  } while (0)
#define READ_A_FR(b_, q_)                                                     \
  do {                                                                        \
    _Pragma("unroll") for (int rf = 0; rf < 2; ++rf)                          \
    _Pragma("unroll") for (int ks = 0; ks < 2; ++ks) {                        \
      const int ra = wr * 128 + (q_)*32 + rf * 16 + m;                        \
      const int ca = (ks * 4 + qd) ^ (ra & 7);                                \
      av[rf][ks] = *(const h16x8*)&lA[b_][ra * 64 + ca * 8];                  \
    }                                                                         \
  } while (0)
#define MFMA_Q(q_)                                                            \
  do {                                                                        \
    _Pragma("unroll") for (int rf = 0; rf < 2; ++rf)                          \
    _Pragma("unroll") for (int cf = 0; cf < 4; ++cf)                          \
    _Pragma("unroll") for (int ks = 0; ks < 2; ++ks)                          \
        acc[(q_)*2 + rf][cf] = __builtin_amdgcn_mfma_f32_16x16x32_f16(        \
            av[rf][ks], bv[cf][ks], acc[(q_)*2 + rf][cf], 0, 0, 0);           \
  } while (0)

#define BAR() __builtin_amdgcn_s_barrier()
#define PRIO(x_) __builtin_amdgcn_s_setprio(x_)
#define VMCNT(n_) asm volatile("s_waitcnt vmcnt(" #n_ ")" ::: "memory")
#define LGKM(n_) asm volatile("s_waitcnt lgkmcnt(" #n_ ")" ::: "memory")

// one steady K-tile; b_/nb_ are LITERAL 0/1 so LDS addressing folds.
// ONE barrier per phase; reads of phase p+1 issue right after MFMA(p).
#define TILE_STEADY(t_, b_, nb_)                                              \
  {                                                                           \
    const int k1 = ((t_) + 1) * 64, k2 = ((t_) + 2) * 64;                     \
    h16x8 av[2][2], bv[4][2];                                                 \
    READ_B_FR(b_);                                                            \
    READ_A_FR(b_, 0);                                                         \
    STAGE_A(1, k1, nb_); STAGE_A(3, k1, nb_);                                 \
    LGKM(8); BAR(); LGKM(0);                                                  \
    PRIO(1); MFMA_Q(0); PRIO(0);                                              \
    READ_A_FR(b_, 1);                                                         \
    STAGE_B(0, k2, b_); STAGE_B(1, k2, b_);                                   \
    BAR(); LGKM(0);                                                           \
    PRIO(1); MFMA_Q(1); PRIO(0);                                              \
    READ_A_FR(b_, 2);                                                         \
    STAGE_B(2, k2, b_); STAGE_B(3, k2, b_);                                   \
    BAR(); LGKM(0);                                                           \
    PRIO(1); MFMA_Q(2); PRIO(0);                                              \
    READ_A_FR(b_, 3);                                                         \
    STAGE_A(0, k2, b_); STAGE_A(2, k2, b_);                                   \
    BAR(); LGKM(0);                                                           \
    PRIO(1); MFMA_Q(3); PRIO(0);                                              \
    VMCNT(6); BAR();                                                          \
  }

  // ---- prologue: tile 0 complete + tile 1's B & A-even (14 loads) ----
  STAGE_B(0, 0, 0); STAGE_B(1, 0, 0); STAGE_B(2, 0, 0); STAGE_B(3, 0, 0);
  STAGE_A(0, 0, 0); STAGE_A(1, 0, 0); STAGE_A(2, 0, 0); STAGE_A(3, 0, 0);
  STAGE_B(0, 64, 1); STAGE_B(1, 64, 1); STAGE_B(2, 64, 1); STAGE_B(3, 64, 1);
  STAGE_A(0, 64, 1); STAGE_A(2, 64, 1);
  VMCNT(6);   // tile 0 fully landed; tile 1's 6 loads may stay in flight
  BAR();

  // ---- steady main loop: 2 K-tiles per iteration (t = 0 .. NKT-3) ----
  for (int tt = 0; tt < NKT - 2; tt += 2) {
    TILE_STEADY(tt, 0, 1);
    TILE_STEADY(tt + 1, 1, 0);
  }

  // ---- peeled tile NKT-2 (buf=0): stage only A-odd(NKT-1); drain all ----
  {
    h16x8 av[2][2], bv[4][2];
    READ_B_FR(0);
    READ_A_FR(0, 0);
    STAGE_A(1, (NKT - 1) * 64, 1); STAGE_A(3, (NKT - 1) * 64, 1);
    LGKM(8); BAR(); LGKM(0);
    PRIO(1); MFMA_Q(0); PRIO(0);
    READ_A_FR(0, 1);
    BAR(); LGKM(0);
    PRIO(1); MFMA_Q(1); PRIO(0);
    READ_A_FR(0, 2);
    BAR(); LGKM(0);
    PRIO(1); MFMA_Q(2); PRIO(0);
    READ_A_FR(0, 3);
    BAR(); LGKM(0);
    PRIO(1); MFMA_Q(3); PRIO(0);
    VMCNT(0); BAR();
  }
  // ---- peeled tile NKT-1 (buf=1): pure compute ----
  {
    h16x8 av[2][2], bv[4][2];
    READ_B_FR(1);
    READ_A_FR(1, 0);
    LGKM(8); BAR(); LGKM(0);
    PRIO(1); MFMA_Q(0); PRIO(0);
    READ_A_FR(1, 1);
    BAR(); LGKM(0);
    PRIO(1); MFMA_Q(1); PRIO(0);
    READ_A_FR(1, 2);
    BAR(); LGKM(0);
    PRIO(1); MFMA_Q(2); PRIO(0);
    READ_A_FR(1, 3);
    BAR(); LGKM(0);
    PRIO(1); MFMA_Q(3); PRIO(0);
  }

  // C/D layout: col = lane&15, row = (lane>>4)*4 + reg  [m89/m91, dtype-indep]
#pragma unroll
  for (int fr = 0; fr < 8; ++fr) {
#pragma unroll
    for (int fc = 0; fc < 4; ++fc) {
#pragma unroll
      for (int rg = 0; rg < 4; ++rg) {
        const int lr = wr * 128 + fr * 16 + qd * 4 + rg;  // row within tile
        const int lc = wc * 64 + fc * 16 + m;             // col within tile
        const size_t idx = (size_t)(bi * 256 + lr) * NN + bj * 256 + lc;
        float v = beta * acc[fr][fc][rg];
        if (alpha != 0.0f) v += alpha * (float)aux[idx];
        if (EPI == 0)
          ((f16*)Out)[idx] = (f16)v;
        else
          ((float*)Out)[idx] = v;
        if (TRI && bi != bj) {  // fused mirror: symmetric product
          const size_t idxT = (size_t)(bj * 256 + lc) * NN + bi * 256 + lr;
          ((f16*)Out)[idxT] = (f16)v;
        }
      }
    }
  }
#undef STAGE_A
#undef STAGE_B
#undef READ_B_FR
#undef READ_A_FR
#undef MFMA_Q
#undef TILE_STEADY
#undef BAR
#undef PRIO
#undef VMCNT
#undef LGKM
}

// ---------------------------------------------------------------------------
// 2-byte transpose, 64x64 LDS tiles (pad +1 to break bank conflicts)
// ---------------------------------------------------------------------------
__global__ void transpose_h(const unsigned short* __restrict__ in,
                            unsigned short* __restrict__ out) {
  __shared__ unsigned short tile[64][65];
  const int tx = threadIdx.x & 63;
  const int ty = threadIdx.x >> 6;
  const int bx = blockIdx.x, by = blockIdx.y;
#pragma unroll
  for (int rr = 0; rr < 16; ++rr) {
    const int row = rr * 4 + ty;
    tile[row][tx] = in[(size_t)(by * 64 + row) * NN + bx * 64 + tx];
  }
  __syncthreads();
#pragma unroll
  for (int rr = 0; rr < 16; ++rr) {
    const int row = rr * 4 + ty;
    out[(size_t)(bx * 64 + row) * NN + by * 64 + tx] = tile[tx][row];
  }
}

// ---------------------------------------------------------------------------
// Power iteration matvec on symmetric f16 A: vout = A*(vin*rsqrt(*snin)),
// atomicAdd ||vout||^2 into *snout. One wave per row.
// ---------------------------------------------------------------------------
__global__ __launch_bounds__(256) void powmv(const f16* __restrict__ A,
                                             const float* __restrict__ vin,
                                             const float* __restrict__ snin,
                                             float* __restrict__ vout,
                                             float* __restrict__ snout) {
  const float scale = rsqrtf(*snin);
  const int row = blockIdx.x * 4 + (threadIdx.x >> 6);
  const int lane = threadIdx.x & 63;
  const f16* arow = A + (size_t)row * NN;
  float acc = 0.0f;
#pragma unroll
  for (int p = 0; p < 8; ++p) {
    const int c = p * 512 + lane * 8;
    const h16x8 av = *(const h16x8*)(arow + c);
    const float4 w0 = *(const float4*)(vin + c);
    const float4 w1 = *(const float4*)(vin + c + 4);
    acc += (float)av[0] * w0.x + (float)av[1] * w0.y + (float)av[2] * w0.z +
           (float)av[3] * w0.w + (float)av[4] * w1.x + (float)av[5] * w1.y +
           (float)av[6] * w1.z + (float)av[7] * w1.w;
  }
  for (int off = 32; off; off >>= 1) acc += __shfl_down(acc, off, 64);
  if (lane == 0) {
    const float u = acc * scale;
    vout[row] = u;
    atomicAdd(snout, u * u);
  }
}

// ---------------------------------------------------------------------------
// init: slots[64] (slot1=1 for ||v0||^2), v0 = +-1/64
// ---------------------------------------------------------------------------
__global__ void init_pw(float* __restrict__ v0, float* __restrict__ slots) {
  const int t = threadIdx.x;
  if (t < 64) slots[t] = (t == 1) ? 1.0f : 0.0f;
  for (int i = t; i < NN; i += 256) {
    const unsigned h = (unsigned)i * 2654435761u;
    v0[i] = ((h >> 16) & 1) ? 0.015625f : -0.015625f;
  }
}

// ---------------------------------------------------------------------------
// ||H||_F^2 -> slots[0]
// ---------------------------------------------------------------------------
__global__ void reduce_sumsq(const float* __restrict__ h, float* __restrict__ slots) {
  float acc = 0.0f;
  const size_t total = (size_t)NN * NN;
  for (size_t i = (size_t)blockIdx.x * blockDim.x + threadIdx.x; i < total;
       i += (size_t)gridDim.x * blockDim.x) {
    const float v = h[i];
    acc += v * v;
  }
  for (int off = 32; off; off >>= 1) acc += __shfl_down(acc, off, 64);
  __shared__ float ws[4];
  const int lane = threadIdx.x & 63, wv = threadIdx.x >> 6;
  if (lane == 0) ws[wv] = acc;
  __syncthreads();
  if (threadIdx.x == 0) atomicAdd(&slots[0], ws[0] + ws[1] + ws[2] + ws[3]);
}

// ---------------------------------------------------------------------------
// H (fp32) -> f16, scaled.
//   mode 0: X0' = H * PRESCALE / ||H||_F          (pre-scale for lambda est)
//   mode 1: X0  = H * PRESCALE / (||H||_F * sqrt(1.10*lam_hat))
// ---------------------------------------------------------------------------
__global__ void scale_cast(const float* __restrict__ h, const float* __restrict__ slots,
                           f16* __restrict__ xb, int mode) {
  float inv = rsqrtf(slots[0]) * PRESCALE;
  if (mode) inv *= rsqrtf(1.10f * sqrtf(slots[1 + NPOW]));
  const size_t i = ((size_t)blockIdx.x * blockDim.x + threadIdx.x) * 4;
  const float4 v = *(const float4*)(h + i);
  union { f16 hh[4]; ushort4 u; } cvt;
  cvt.hh[0] = (f16)(v.x * inv);
  cvt.hh[1] = (f16)(v.y * inv);
  cvt.hh[2] = (f16)(v.z * inv);
  cvt.hh[3] = (f16)(v.w * inv);
  *(ushort4*)(xb + i) = cvt.u;
}

// ---------------------------------------------------------------------------
// A *= 1/(1.10*lam_hat)  so A0 = X0^T X0 for the mode-1-scaled X0.
// ---------------------------------------------------------------------------
__global__ void rescale_f16(f16* __restrict__ a, const float* __restrict__ slots) {
  const float cA = 1.0f / (1.10f * sqrtf(slots[1 + NPOW]));
  const size_t i = ((size_t)blockIdx.x * 256 + threadIdx.x) * 8;
  h16x8 v = *(h16x8*)(a + i);
  h16x8 o;
#pragma unroll
  for (int j = 0; j < 8; ++j) o[j] = (f16)((float)v[j] * cA);
  *(h16x8*)(a + i) = o;
}

// ---------------------------------------------------------------------------
// Polar factor via sigma_max-normalized quintic Newton-Schulz, fp16 GEMMs.
//   8x Muon growth + 2x tangent polish (15/8,-5/4,3/8).
//   ws: P0 [0,32M) | P1 [32M,64M) | Ab [64M,96M)
//   d_out: v0/v1/slots in first 48KB (preamble only), Bb at +32MB; final B
//   goes to the dead ws X^T buffer so the fp32 C-write never races it.
// ---------------------------------------------------------------------------
extern "C" void kernel_launch(void* const* d_in, const int* in_sizes, int n_in,
                              void* d_out, int out_size, void* d_ws, size_t ws_size,
                              hipStream_t stream) {
  (void)in_sizes; (void)n_in; (void)out_size; (void)ws_size;
  const float* H = (const float*)d_in[0];
  float* out = (float*)d_out;
  char* ws = (char*)d_ws;

  f16* P0 = (f16*)ws;
  f16* P1 = (f16*)(ws + ((size_t)32 << 20));
  f16* Ab = (f16*)(ws + ((size_t)64 << 20));
  f16* Bb = (f16*)((char*)d_out + ((size_t)32 << 20));
  float* v0 = (float*)d_out;
  float* v1 = (float*)((char*)d_out + 16384);
  float* slots = (float*)((char*)d_out + 32768);

  const dim3 gfull(16, 16), tbg(512), tb(256), gt(64, 64);

  // --- preamble: Frobenius scale, A' = X0'^T X0', power-iterate lambda_max ---
  init_pw<<<1, 256, 0, stream>>>(v0, slots);
  reduce_sumsq<<<1024, 256, 0, stream>>>(H, slots);
  scale_cast<<<(NN * (size_t)NN) / 4 / 256, 256, 0, stream>>>(H, slots, P0, 0);
  transpose_h<<<gt, tb, 0, stream>>>((const unsigned short*)P0, (unsigned short*)P1);
  gemm_nt<0, 1><<<NTRI, tbg, 0, stream>>>(P1, P1, Ab, (f16*)nullptr, 0.0f, 1.0f);
  for (int k = 0; k < NPOW; ++k) {
    const float* vi = (k & 1) ? v1 : v0;
    float* vo = (k & 1) ? v0 : v1;
    powmv<<<1024, 256, 0, stream>>>(Ab, vi, &slots[1 + k], vo, &slots[2 + k]);
  }
  rescale_f16<<<(NN * (size_t)NN) / 8 / 256, 256, 0, stream>>>(Ab, slots);
  scale_cast<<<(NN * (size_t)NN) / 4 / 256, 256, 0, stream>>>(H, slots, P0, 1);

  // --- quintic iterations ---
  f16* X = P0;
  f16* Y = P1;
  const float GA = 3.4445f, GB = -4.7750f, GC = 2.0315f;  // Muon growth
  const float PA = 1.875f, PB = -1.25f, PC = 0.375f;       // tangent polish

  for (int it = 0; it < NITER; ++it) {
    const bool polish = it >= NGROW;
    const bool last = (it == NITER - 1);
    const float qa = polish ? PA : GA, qb = polish ? PB : GB, qc = polish ? PC : GC;

    if (it > 0) {  // iteration 0 reuses the preamble's (rescaled) A
      transpose_h<<<gt, tb, 0, stream>>>((const unsigned short*)X, (unsigned short*)Y);
      gemm_nt<0, 1><<<NTRI, tbg, 0, stream>>>(Y, Y, Ab, (f16*)nullptr, 0.0f, 1.0f);
    }
    f16* Bdst = last ? Y : Bb;  // final B must not alias d_out (race w/ C-write)
    gemm_nt<0, 1><<<NTRI, tbg, 0, stream>>>(Ab, Ab, Bdst, Ab, qb, qc);
    if (!last) {
      gemm_nt<0, 0><<<gfull, tbg, 0, stream>>>(X, Bdst, Y, X, qa, 1.0f);
      f16* t = X; X = Y; Y = t;
    } else {
      gemm_nt<1, 0><<<gfull, tbg, 0, stream>>>(X, Bdst, out, X, qa, 1.0f);
    }
  }
}

// Round 4
// 4454.056 us; speedup vs baseline: 1.0570x; 1.0570x over previous
//
#include <hip/hip_runtime.h>
#include <hip/hip_bf16.h>
#include <hip/hip_fp16.h>

#define NN 4096
#define NGROW 8
#define NPOL 2
#define NITER (NGROW + NPOL)
#define NPOW 12
#define NKT (NN / 64)     // 64 K-tiles of BK=64
#define NTRI 136          // 16*17/2 lower-triangle 256-tiles
#define PRESCALE 32.0f    // keeps pre-rescale A entries in f16 normal range

using f16 = _Float16;
typedef __attribute__((ext_vector_type(4))) float f32x4;
typedef __attribute__((ext_vector_type(8))) f16 h16x8;

// ---------------------------------------------------------------------------
// async global->LDS, 16B per lane. LDS side MUST be wave-uniform base + lane*16.
// ---------------------------------------------------------------------------
__device__ inline void gl_lds16(const void* g, void* l) {
  __builtin_amdgcn_global_load_lds(
      (const __attribute__((address_space(1))) unsigned int*)(unsigned long long)(uintptr_t)g,
      (__attribute__((address_space(3))) unsigned int*)(uintptr_t)l,
      16, 0, 0);
}

// ---------------------------------------------------------------------------
// NT GEMM, 256x256 tile, BK=64. R3 post-mortem: tile time == serial sum of
// LDS-read burst + MFMA burst (5138 cyc == 2304+2483+waits) because the
// fragment registers were REUSED each phase -> WAR hazard -> compiler cannot
// overlap reads(p+1) with MFMA(p). Fix: register-double-buffered fragments
// (avA/avB alternate per phase, bv0/bv1 per tile) + sched_group_barrier
// interleave so ds_reads issue BETWEEN MFMAs (dep-free now), + tile-boundary
// sync moved one phase early (vmcnt(4)+BAR at end of p2) so p3 prefetches
// next tile's B-frags and q0 A-frags from the other LDS buffer under MFMA q3.
//
// Per K-tile t (buf b=t&1, nb=1-b; BVC=bv[t&1], BVN=bv[1-(t&1)]):
//  p0: MFMA q0(avA,BVC) | rd av(t,q1)->avB      | stage A1A3(t+1)->nb | BAR
//  p1: MFMA q1(avB,BVC) | rd av(t,q2)->avA      | stage B01(t+2)->b   | BAR
//  p2: MFMA q2(avA,BVC) | rd av(t,q3)->avB      | stage B23(t+2)->b   | VMCNT(4) BAR
//  p3: MFMA q3(avB,BVC) | rd bv(t+1)->BVN,
//                         av(t+1,q0)->avA (nb)  | stage A02(t+2)->b   | BAR
// vmcnt ledger: VMCNT(4)@p2(t) keeps newest 4 = {B01,B23}(t+2), drains all 8
// of tile t+1 ({B01,B23}(t+1)@p1,p2(t-1), A02(t+1)@p3(t-1), A1A3(t+1)@p0(t))
// -> the BAR after it publishes buffer nb for p3's prefetch reads.
// Write-hazard ledger (stage vs last ds_read of region, barriers apart):
//  A02(t+2)->b @p3(t): A0/A2(b) last read p0(t) (q1)            [3 bars]
//  B01/B23(t+2)->b @p1/p2(t): B(t) last read p3(t-1) (prefetch) [2-3 bars]
//  A1A3(t+1)->nb @p0(t): A1/A3(nb) last read p2(t-1) (q3)       [2 bars]
// sched_group_barrier masks: MFMA=0x8, DS_READ=0x100, VMEM=0x30.
// ---------------------------------------------------------------------------
template <int EPI, int TRI>
__global__ __launch_bounds__(512, 2) void gemm_nt(
    const f16* __restrict__ P, const f16* __restrict__ Q,
    void* __restrict__ Out, const f16* __restrict__ aux,
    float alpha, float beta) {
  int bi, bj;
  if (TRI) {
    const int t = blockIdx.x;
    int r = (int)((sqrtf(8.0f * (float)t + 1.0f) - 1.0f) * 0.5f);
    while ((r + 1) * (r + 2) / 2 <= t) ++r;
    while (r * (r + 1) / 2 > t) --r;
    bi = r;
    bj = t - r * (r + 1) / 2;
  } else {
    bi = blockIdx.x;
    bj = blockIdx.y;
  }

  __shared__ f16 lA[2][256 * 64];   // 32 KB x2
  __shared__ f16 lB[2][256 * 64];   // 32 KB x2  (total 128 KiB)

  const int tid = threadIdx.x;
  const int lane = tid & 63;
  const int wv = tid >> 6;      // 0..7
  const int wr = wv >> 2;       // 0..1  (M)
  const int wc = wv & 3;        // 0..3  (N)
  const int m = lane & 15;
  const int qd = lane >> 4;     // 0..3
  const int srow = tid >> 3;    // 0..63 row within a 64-row stage unit
  const int schk = tid & 7;     // 8-f16 chunk within row

  f32x4 acc[8][4] = {};
  // double-buffered MFMA fragments (all indices compile-time constant)
  h16x8 avA[2][2], avB[2][2];   // per-phase alternation
  h16x8 bv0[4][2], bv1[4][2];   // per-tile alternation

// stage unit u (64 rows) of A/B for K-offset kk into buffer b_.
// global source pre-swizzled (chunk ^ row&7), LDS dest linear (G21).
#define STAGE_A(u_, kk_, b_)                                                  \
  do {                                                                        \
    const int rr_ = (u_)*64 + srow;                                           \
    gl_lds16(P + (size_t)(bi * 256 + rr_) * NN + (kk_) + ((schk ^ (srow & 7)) * 8), \
             &lA[b_][(u_)*4096 + tid * 8]);                                   \
  } while (0)
#define STAGE_B(u_, kk_, b_)                                                  \
  do {                                                                        \
    const int rr_ = (u_)*64 + srow;                                           \
    gl_lds16(Q + (size_t)(bj * 256 + rr_) * NN + (kk_) + ((schk ^ (srow & 7)) * 8), \
             &lB[b_][(u_)*4096 + tid * 8]);                                   \
  } while (0)

#define READ_AV(dst_, b_, q_)                                                 \
  do {                                                                        \
    _Pragma("unroll") for (int rf = 0; rf < 2; ++rf)                          \
    _Pragma("unroll") for (int ks = 0; ks < 2; ++ks) {                        \
      const int ra = wr * 128 + (q_)*32 + rf * 16 + m;                        \
      const int ca = (ks * 4 + qd) ^ (ra & 7);                                \
      dst_[rf][ks] = *(const h16x8*)&lA[b_][ra * 64 + ca * 8];                \
    }                                                                         \
  } while (0)
#define READ_BV(dst_, b_)                                                     \
  do {                                                                        \
    _Pragma("unroll") for (int cf = 0; cf < 4; ++cf)                          \
    _Pragma("unroll") for (int ks = 0; ks < 2; ++ks) {                        \
      const int rb = wc * 64 + cf * 16 + m;                                   \
      const int cb = (ks * 4 + qd) ^ (rb & 7);                                \
      dst_[cf][ks] = *(const h16x8*)&lB[b_][rb * 64 + cb * 8];                \
    }                                                                         \
  } while (0)
#define MFMA_Q(q_, A_, B_)                                                    \
  do {                                                                        \
    _Pragma("unroll") for (int rf = 0; rf < 2; ++rf)                          \
    _Pragma("unroll") for (int cf = 0; cf < 4; ++cf)                          \
    _Pragma("unroll") for (int ks = 0; ks < 2; ++ks)                          \
        acc[(q_)*2 + rf][cf] = __builtin_amdgcn_mfma_f32_16x16x32_f16(        \
            A_[rf][ks], B_[cf][ks], acc[(q_)*2 + rf][cf], 0, 0, 0);           \
  } while (0)

#define BAR() __builtin_amdgcn_s_barrier()
#define VMCNT(n_) asm volatile("s_waitcnt vmcnt(" #n_ ")" ::: "memory")
#define SGB(m_, n_) __builtin_amdgcn_sched_group_barrier(m_, n_, 0)
// 16 MFMA + 4 ds_read + 2 vmem(gl_lds) interleaved
#define SGB_RD4_ST2()                                                         \
  do { SGB(0x8,2); SGB(0x100,1); SGB(0x8,2); SGB(0x100,1); SGB(0x8,2);        \
       SGB(0x100,1); SGB(0x8,2); SGB(0x100,1); SGB(0x8,2); SGB(0x30,1);       \
       SGB(0x8,3); SGB(0x30,1); SGB(0x8,3); } while (0)
// 16 MFMA + 4 ds_read
#define SGB_RD4_ST0()                                                         \
  do { SGB(0x8,3); SGB(0x100,1); SGB(0x8,3); SGB(0x100,1); SGB(0x8,3);        \
       SGB(0x100,1); SGB(0x8,3); SGB(0x100,1); SGB(0x8,4); } while (0)
// 16 MFMA + 12 ds_read + 2 vmem
#define SGB_RD12_ST2()                                                        \
  do { SGB(0x100,2); SGB(0x8,2); SGB(0x100,2); SGB(0x8,2); SGB(0x100,2);      \
       SGB(0x8,2); SGB(0x100,2); SGB(0x8,2); SGB(0x100,2); SGB(0x8,2);        \
       SGB(0x100,2); SGB(0x8,2); SGB(0x30,1); SGB(0x8,2); SGB(0x30,1);        \
       SGB(0x8,2); } while (0)
// 16 MFMA + 12 ds_read
#define SGB_RD12_ST0()                                                        \
  do { SGB(0x100,2); SGB(0x8,2); SGB(0x100,2); SGB(0x8,2); SGB(0x100,2);      \
       SGB(0x8,2); SGB(0x100,2); SGB(0x8,2); SGB(0x100,2); SGB(0x8,2);        \
       SGB(0x100,2); SGB(0x8,2); SGB(0x8,4); } while (0)

#define TILE_STEADY(t_, b_, nb_, BVC_, BVN_)                                  \
  {                                                                           \
    const int k1 = ((t_) + 1) * 64, k2 = ((t_) + 2) * 64;                     \
    /* p0 */                                                                  \
    READ_AV(avB, b_, 1);                                                      \
    STAGE_A(1, k1, nb_); STAGE_A(3, k1, nb_);                                 \
    MFMA_Q(0, avA, BVC_);                                                     \
    SGB_RD4_ST2(); BAR();                                                     \
    /* p1 */                                                                  \
    READ_AV(avA, b_, 2);                                                      \
    STAGE_B(0, k2, b_); STAGE_B(1, k2, b_);                                   \
    MFMA_Q(1, avB, BVC_);                                                     \
    SGB_RD4_ST2(); BAR();                                                     \
    /* p2 */                                                                  \
    READ_AV(avB, b_, 3);                                                      \
    STAGE_B(2, k2, b_); STAGE_B(3, k2, b_);                                   \
    MFMA_Q(2, avA, BVC_);                                                     \
    SGB_RD4_ST2(); VMCNT(4); BAR();                                           \
    /* p3: prefetch next tile's B + q0-A from the other buffer */             \
    READ_BV(BVN_, nb_);                                                       \
    READ_AV(avA, nb_, 0);                                                     \
    STAGE_A(0, k2, b_); STAGE_A(2, k2, b_);                                   \
    MFMA_Q(3, avB, BVC_);                                                     \
    SGB_RD12_ST2(); BAR();                                                    \
  }

  // ---- prologue: tile 0 complete + tile 1's B & A-even (14 loads) ----
  STAGE_B(0, 0, 0); STAGE_B(1, 0, 0); STAGE_B(2, 0, 0); STAGE_B(3, 0, 0);
  STAGE_A(0, 0, 0); STAGE_A(1, 0, 0); STAGE_A(2, 0, 0); STAGE_A(3, 0, 0);
  STAGE_B(0, 64, 1); STAGE_B(1, 64, 1); STAGE_B(2, 64, 1); STAGE_B(3, 64, 1);
  STAGE_A(0, 64, 1); STAGE_A(2, 64, 1);
  VMCNT(6);   // tile 0 fully landed; tile 1's 6 loads may stay in flight
  BAR();
  // initial register state: bv(0) + av(0,q0); extra BAR isolates the
  // scheduling region so the SGB groups in p0 see exactly p0's instrs.
  READ_BV(bv0, 0);
  READ_AV(avA, 0, 0);
  BAR();

  // ---- steady main loop: 2 K-tiles per iteration (t = 0 .. NKT-3) ----
  for (int tt = 0; tt < NKT - 2; tt += 2) {
    TILE_STEADY(tt, 0, 1, bv0, bv1);
    TILE_STEADY(tt + 1, 1, 0, bv1, bv0);
  }

  // ---- peeled tile NKT-2 (b=0, nb=1, BVC=bv0): last stage is A1A3(NKT-1) ----
  {
    READ_AV(avB, 0, 1);
    STAGE_A(1, (NKT - 1) * 64, 1); STAGE_A(3, (NKT - 1) * 64, 1);
    MFMA_Q(0, avA, bv0);
    SGB_RD4_ST2(); BAR();
    READ_AV(avA, 0, 2);
    MFMA_Q(1, avB, bv0);
    SGB_RD4_ST0(); BAR();
    READ_AV(avB, 0, 3);
    MFMA_Q(2, avA, bv0);
    SGB_RD4_ST0(); VMCNT(0); BAR();
    READ_BV(bv1, 1);
    READ_AV(avA, 1, 0);
    MFMA_Q(3, avB, bv0);
    SGB_RD12_ST0(); BAR();
  }
  // ---- peeled tile NKT-1 (b=1, BVC=bv1): pure compute ----
  {
    READ_AV(avB, 1, 1);
    MFMA_Q(0, avA, bv1);
    SGB_RD4_ST0(); BAR();
    READ_AV(avA, 1, 2);
    MFMA_Q(1, avB, bv1);
    SGB_RD4_ST0(); BAR();
    READ_AV(avB, 1, 3);
    MFMA_Q(2, avA, bv1);
    SGB_RD4_ST0(); BAR();
    MFMA_Q(3, avB, bv1);
  }

  // C/D layout: col = lane&15, row = (lane>>4)*4 + reg  [m89/m91, dtype-indep]
#pragma unroll
  for (int fr = 0; fr < 8; ++fr) {
#pragma unroll
    for (int fc = 0; fc < 4; ++fc) {
#pragma unroll
      for (int rg = 0; rg < 4; ++rg) {
        const int lr = wr * 128 + fr * 16 + qd * 4 + rg;  // row within tile
        const int lc = wc * 64 + fc * 16 + m;             // col within tile
        const size_t idx = (size_t)(bi * 256 + lr) * NN + bj * 256 + lc;
        float v = beta * acc[fr][fc][rg];
        if (alpha != 0.0f) v += alpha * (float)aux[idx];
        if (EPI == 0)
          ((f16*)Out)[idx] = (f16)v;
        else
          ((float*)Out)[idx] = v;
        if (TRI && bi != bj) {  // fused mirror: symmetric product
          const size_t idxT = (size_t)(bj * 256 + lc) * NN + bi * 256 + lr;
          ((f16*)Out)[idxT] = (f16)v;
        }
      }
    }
  }
#undef STAGE_A
#undef STAGE_B
#undef READ_AV
#undef READ_BV
#undef MFMA_Q
#undef TILE_STEADY
#undef BAR
#undef VMCNT
#undef SGB
#undef SGB_RD4_ST2
#undef SGB_RD4_ST0
#undef SGB_RD12_ST2
#undef SGB_RD12_ST0
}

// ---------------------------------------------------------------------------
// 2-byte transpose, 64x64 LDS tiles (pad +1 to break bank conflicts)
// ---------------------------------------------------------------------------
__global__ void transpose_h(const unsigned short* __restrict__ in,
                            unsigned short* __restrict__ out) {
  __shared__ unsigned short tile[64][65];
  const int tx = threadIdx.x & 63;
  const int ty = threadIdx.x >> 6;
  const int bx = blockIdx.x, by = blockIdx.y;
#pragma unroll
  for (int rr = 0; rr < 16; ++rr) {
    const int row = rr * 4 + ty;
    tile[row][tx] = in[(size_t)(by * 64 + row) * NN + bx * 64 + tx];
  }
  __syncthreads();
#pragma unroll
  for (int rr = 0; rr < 16; ++rr) {
    const int row = rr * 4 + ty;
    out[(size_t)(bx * 64 + row) * NN + by * 64 + tx] = tile[tx][row];
  }
}

// ---------------------------------------------------------------------------
// Power iteration matvec on symmetric f16 A: vout = A*(vin*rsqrt(*snin)),
// atomicAdd ||vout||^2 into *snout. One wave per row.
// ---------------------------------------------------------------------------
__global__ __launch_bounds__(256) void powmv(const f16* __restrict__ A,
                                             const float* __restrict__ vin,
                                             const float* __restrict__ snin,
                                             float* __restrict__ vout,
                                             float* __restrict__ snout) {
  const float scale = rsqrtf(*snin);
  const int row = blockIdx.x * 4 + (threadIdx.x >> 6);
  const int lane = threadIdx.x & 63;
  const f16* arow = A + (size_t)row * NN;
  float acc = 0.0f;
#pragma unroll
  for (int p = 0; p < 8; ++p) {
    const int c = p * 512 + lane * 8;
    const h16x8 av = *(const h16x8*)(arow + c);
    const float4 w0 = *(const float4*)(vin + c);
    const float4 w1 = *(const float4*)(vin + c + 4);
    acc += (float)av[0] * w0.x + (float)av[1] * w0.y + (float)av[2] * w0.z +
           (float)av[3] * w0.w + (float)av[4] * w1.x + (float)av[5] * w1.y +
           (float)av[6] * w1.z + (float)av[7] * w1.w;
  }
  for (int off = 32; off; off >>= 1) acc += __shfl_down(acc, off, 64);
  if (lane == 0) {
    const float u = acc * scale;
    vout[row] = u;
    atomicAdd(snout, u * u);
  }
}

// ---------------------------------------------------------------------------
// init: slots[64] (slot1=1 for ||v0||^2), v0 = +-1/64
// ---------------------------------------------------------------------------
__global__ void init_pw(float* __restrict__ v0, float* __restrict__ slots) {
  const int t = threadIdx.x;
  if (t < 64) slots[t] = (t == 1) ? 1.0f : 0.0f;
  for (int i = t; i < NN; i += 256) {
    const unsigned h = (unsigned)i * 2654435761u;
    v0[i] = ((h >> 16) & 1) ? 0.015625f : -0.015625f;
  }
}

// ---------------------------------------------------------------------------
// ||H||_F^2 -> slots[0]
// ---------------------------------------------------------------------------
__global__ void reduce_sumsq(const float* __restrict__ h, float* __restrict__ slots) {
  float acc = 0.0f;
  const size_t total = (size_t)NN * NN;
  for (size_t i = (size_t)blockIdx.x * blockDim.x + threadIdx.x; i < total;
       i += (size_t)gridDim.x * blockDim.x) {
    const float v = h[i];
    acc += v * v;
  }
  for (int off = 32; off; off >>= 1) acc += __shfl_down(acc, off, 64);
  __shared__ float ws[4];
  const int lane = threadIdx.x & 63, wv = threadIdx.x >> 6;
  if (lane == 0) ws[wv] = acc;
  __syncthreads();
  if (threadIdx.x == 0) atomicAdd(&slots[0], ws[0] + ws[1] + ws[2] + ws[3]);
}

// ---------------------------------------------------------------------------
// H (fp32) -> f16, scaled.
//   mode 0: X0' = H * PRESCALE / ||H||_F          (pre-scale for lambda est)
//   mode 1: X0  = H * PRESCALE / (||H||_F * sqrt(1.10*lam_hat))
// ---------------------------------------------------------------------------
__global__ void scale_cast(const float* __restrict__ h, const float* __restrict__ slots,
                           f16* __restrict__ xb, int mode) {
  float inv = rsqrtf(slots[0]) * PRESCALE;
  if (mode) inv *= rsqrtf(1.10f * sqrtf(slots[1 + NPOW]));
  const size_t i = ((size_t)blockIdx.x * blockDim.x + threadIdx.x) * 4;
  const float4 v = *(const float4*)(h + i);
  union { f16 hh[4]; ushort4 u; } cvt;
  cvt.hh[0] = (f16)(v.x * inv);
  cvt.hh[1] = (f16)(v.y * inv);
  cvt.hh[2] = (f16)(v.z * inv);
  cvt.hh[3] = (f16)(v.w * inv);
  *(ushort4*)(xb + i) = cvt.u;
}

// ---------------------------------------------------------------------------
// A *= 1/(1.10*lam_hat)  so A0 = X0^T X0 for the mode-1-scaled X0.
// ---------------------------------------------------------------------------
__global__ void rescale_f16(f16* __restrict__ a, const float* __restrict__ slots) {
  const float cA = 1.0f / (1.10f * sqrtf(slots[1 + NPOW]));
  const size_t i = ((size_t)blockIdx.x * 256 + threadIdx.x) * 8;
  h16x8 v = *(h16x8*)(a + i);
  h16x8 o;
#pragma unroll
  for (int j = 0; j < 8; ++j) o[j] = (f16)((float)v[j] * cA);
  *(h16x8*)(a + i) = o;
}

// ---------------------------------------------------------------------------
// Polar factor via sigma_max-normalized quintic Newton-Schulz, fp16 GEMMs.
//   8x Muon growth + 2x tangent polish (15/8,-5/4,3/8).
//   ws: P0 [0,32M) | P1 [32M,64M) | Ab [64M,96M)
//   d_out: v0/v1/slots in first 48KB (preamble only), Bb at +32MB; final B
//   goes to the dead ws X^T buffer so the fp32 C-write never races it.
// ---------------------------------------------------------------------------
extern "C" void kernel_launch(void* const* d_in, const int* in_sizes, int n_in,
                              void* d_out, int out_size, void* d_ws, size_t ws_size,
                              hipStream_t stream) {
  (void)in_sizes; (void)n_in; (void)out_size; (void)ws_size;
  const float* H = (const float*)d_in[0];
  float* out = (float*)d_out;
  char* ws = (char*)d_ws;

  f16* P0 = (f16*)ws;
  f16* P1 = (f16*)(ws + ((size_t)32 << 20));
  f16* Ab = (f16*)(ws + ((size_t)64 << 20));
  f16* Bb = (f16*)((char*)d_out + ((size_t)32 << 20));
  float* v0 = (float*)d_out;
  float* v1 = (float*)((char*)d_out + 16384);
  float* slots = (float*)((char*)d_out + 32768);

  const dim3 gfull(16, 16), tbg(512), tb(256), gt(64, 64);

  // --- preamble: Frobenius scale, A' = X0'^T X0', power-iterate lambda_max ---
  init_pw<<<1, 256, 0, stream>>>(v0, slots);
  reduce_sumsq<<<1024, 256, 0, stream>>>(H, slots);
  scale_cast<<<(NN * (size_t)NN) / 4 / 256, 256, 0, stream>>>(H, slots, P0, 0);
  transpose_h<<<gt, tb, 0, stream>>>((const unsigned short*)P0, (unsigned short*)P1);
  gemm_nt<0, 1><<<NTRI, tbg, 0, stream>>>(P1, P1, Ab, (f16*)nullptr, 0.0f, 1.0f);
  for (int k = 0; k < NPOW; ++k) {
    const float* vi = (k & 1) ? v1 : v0;
    float* vo = (k & 1) ? v0 : v1;
    powmv<<<1024, 256, 0, stream>>>(Ab, vi, &slots[1 + k], vo, &slots[2 + k]);
  }
  rescale_f16<<<(NN * (size_t)NN) / 8 / 256, 256, 0, stream>>>(Ab, slots);
  scale_cast<<<(NN * (size_t)NN) / 4 / 256, 256, 0, stream>>>(H, slots, P0, 1);

  // --- quintic iterations ---
  f16* X = P0;
  f16* Y = P1;
  const float GA = 3.4445f, GB = -4.7750f, GC = 2.0315f;  // Muon growth
  const float PA = 1.875f, PB = -1.25f, PC = 0.375f;       // tangent polish

  for (int it = 0; it < NITER; ++it) {
    const bool polish = it >= NGROW;
    const bool last = (it == NITER - 1);
    const float qa = polish ? PA : GA, qb = polish ? PB : GB, qc = polish ? PC : GC;

    if (it > 0) {  // iteration 0 reuses the preamble's (rescaled) A
      transpose_h<<<gt, tb, 0, stream>>>((const unsigned short*)X, (unsigned short*)Y);
      gemm_nt<0, 1><<<NTRI, tbg, 0, stream>>>(Y, Y, Ab, (f16*)nullptr, 0.0f, 1.0f);
    }
    f16* Bdst = last ? Y : Bb;  // final B must not alias d_out (race w/ C-write)
    gemm_nt<0, 1><<<NTRI, tbg, 0, stream>>>(Ab, Ab, Bdst, Ab, qb, qc);
    if (!last) {
      gemm_nt<0, 0><<<gfull, tbg, 0, stream>>>(X, Bdst, Y, X, qa, 1.0f);
      f16* t = X; X = Y; Y = t;
    } else {
      gemm_nt<1, 0><<<gfull, tbg, 0, stream>>>(X, Bdst, out, X, qa, 1.0f);
    }
  }
}